// Round 1
// baseline (666.951 us; speedup 1.0000x reference)
//
#include <hip/hip_runtime.h>

typedef __attribute__((ext_vector_type(8))) short bf16x8;
typedef __attribute__((ext_vector_type(4))) float f32x4;

#define MFMA16(a, b, c) __builtin_amdgcn_mfma_f32_16x16x32_bf16((a), (b), (c), 0, 0, 0)

__device__ __forceinline__ short f2bf(float f) {
  unsigned u = __builtin_bit_cast(unsigned, f);
  u = (u + 0x7fffu + ((u >> 16) & 1u)) >> 16;  // round-to-nearest-even
  return (short)u;
}

// XOR swizzle within a row: spreads stride-row b128 reads across banks (Guideline 4)
__device__ __forceinline__ unsigned swz(int row, unsigned inner) {
  return inner ^ (unsigned)((row & 7) << 4);
}

// ---- LDS layout (bytes), buffers overlaid across phases ----
// Region A [0, 32768):      xs  [64][128] bf16 (phases 0-1)  ->  att [4][64][64] bf16 (phases 2-3)
// Region B [32768, 65536):  qk  [64][256] bf16, q bytes [0,256) k [256,512) (phases 1-2)
//                           ->  o2 [64][128] bf16 (phases 3-4)
// Region C [65536, 81920):  vT  [4][32][64] bf16 (phases 1-3)
#define XS_OFF 0u
#define ATT_OFF 0u
#define QK_OFF 32768u
#define O2_OFF 32768u
#define VT_OFF 65536u
#define SMEM_BYTES 81920

extern "C" __global__ void __launch_bounds__(256)
wattn_prep(const float* __restrict__ qkv_w, const float* __restrict__ proj_w,
           short* __restrict__ wqo, short* __restrict__ wpo) {
  const int i = blockIdx.x * 256 + threadIdx.x;
  if (i < 49152) wqo[i] = f2bf(qkv_w[i]);
  if (i < 16384) wpo[i] = f2bf(proj_w[i]);
}

extern "C" __global__ void __launch_bounds__(512, 4)
wattn_fused(const float* __restrict__ x,
            const float* __restrict__ mask,
            const float* __restrict__ qkv_b,
            const float* __restrict__ proj_b,
            const float* __restrict__ bias_table,
            const short* __restrict__ wq,
            const short* __restrict__ wp,
            float* __restrict__ out) {
  extern __shared__ char smem[];
  const int tid = threadIdx.x;
  const int lane = tid & 63;
  const int wv = tid >> 6;       // wave 0..7
  const int l15 = lane & 15;
  const int kg = lane >> 4;      // k-group 0..3
  const int b = blockIdx.x;
  const int w = b & 63;          // mask window index (b % nW)

  // ---------- phase 0: x[b] -> xs bf16 (rows >=49 zeroed) ----------
  {
    const int r = tid >> 3;  // 0..63
    const int c = tid & 7;   // 16-float chunk within row
    bf16x8 lo, hi;
#pragma unroll
    for (int i = 0; i < 8; ++i) { lo[i] = 0; hi[i] = 0; }
    if (r < 49) {
      const float* xr = x + (size_t)b * 6272 + (size_t)r * 128 + c * 16;
#pragma unroll
      for (int i = 0; i < 8; ++i) lo[i] = f2bf(xr[i]);
#pragma unroll
      for (int i = 0; i < 8; ++i) hi[i] = f2bf(xr[8 + i]);
    }
    char* base = smem + XS_OFF + r * 256;
    *(bf16x8*)(base + swz(r, c * 32)) = lo;
    *(bf16x8*)(base + swz(r, c * 32 + 16)) = hi;
  }
  __syncthreads();

  // ---------- phase 1: QKV GEMM [64x128] @ [128x384] ----------
  // wave wv owns output cols [wv*48, wv*48+48) = 3 n-tiles
  {
    const float qscale = 0.17677669529663687f;  // 32^-0.5
#pragma unroll
    for (int nt = 0; nt < 3; ++nt) {
      const int n0 = wv * 48 + nt * 16;
      const int oc = n0 + l15;
      bf16x8 bw[4];
#pragma unroll
      for (int kk = 0; kk < 4; ++kk)
        bw[kk] = *(const bf16x8*)(wq + (size_t)oc * 128 + kk * 32 + kg * 8);
      f32x4 acc[4];
#pragma unroll
      for (int m = 0; m < 4; ++m) { acc[m][0] = 0.f; acc[m][1] = 0.f; acc[m][2] = 0.f; acc[m][3] = 0.f; }
#pragma unroll
      for (int kk = 0; kk < 4; ++kk) {
#pragma unroll
        for (int m = 0; m < 4; ++m) {
          const int r = m * 16 + l15;
          bf16x8 af = *(const bf16x8*)(smem + XS_OFF + r * 256 + swz(r, kk * 64 + kg * 16));
          acc[m] = MFMA16(af, bw[kk], acc[m]);
        }
      }
      const float bo = qkv_b[oc];
      const int which = n0 >> 7;  // 0=q 1=k 2=v, uniform per wave*nt
#pragma unroll
      for (int m = 0; m < 4; ++m) {
#pragma unroll
        for (int r4 = 0; r4 < 4; ++r4) {
          const int t = m * 16 + kg * 4 + r4;
          float v = acc[m][r4] + bo;
          if (which == 0) {
            v *= qscale;
            *(short*)(smem + QK_OFF + t * 512 + swz(t, (oc & 127) * 2)) = f2bf(v);
          } else if (which == 1) {
            *(short*)(smem + QK_OFF + t * 512 + 256 + swz(t, (oc & 127) * 2)) = f2bf(v);
          } else {
            const int hd = oc & 127;
            const int h = hd >> 5, d = hd & 31;
            *(short*)(smem + VT_OFF + h * 4096 + d * 128 + swz(d, t * 2)) = f2bf(v);
          }
        }
      }
    }
  }
  __syncthreads();

  // ---------- phase 2: attn = q@k^T + bias + mask, per head ----------
  // wave (h = wv>>1, mh = wv&1) owns rows [mh*32, mh*32+32) of head h
  {
    const int h = wv >> 1, mh = wv & 1;
    bf16x8 aq[2];
#pragma unroll
    for (int mi = 0; mi < 2; ++mi) {
      const int t = (mh * 2 + mi) * 16 + l15;
      aq[mi] = *(const bf16x8*)(smem + QK_OFF + t * 512 + swz(t, h * 64 + kg * 16));
    }
    f32x4 acc[2][4];
#pragma unroll
    for (int mi = 0; mi < 2; ++mi)
#pragma unroll
      for (int nt = 0; nt < 4; ++nt) { acc[mi][nt][0] = 0.f; acc[mi][nt][1] = 0.f; acc[mi][nt][2] = 0.f; acc[mi][nt][3] = 0.f; }
#pragma unroll
    for (int nt = 0; nt < 4; ++nt) {
      const int s = nt * 16 + l15;
      bf16x8 bk = *(const bf16x8*)(smem + QK_OFF + s * 512 + 256 + swz(s, h * 64 + kg * 16));
      acc[0][nt] = MFMA16(aq[0], bk, acc[0][nt]);
      acc[1][nt] = MFMA16(aq[1], bk, acc[1][nt]);
    }
    const float* mw = mask + (size_t)w * 2401;
#pragma unroll
    for (int mi = 0; mi < 2; ++mi) {
#pragma unroll
      for (int nt = 0; nt < 4; ++nt) {
#pragma unroll
        for (int r4 = 0; r4 < 4; ++r4) {
          const int t = (mh * 2 + mi) * 16 + kg * 4 + r4;
          const int s = nt * 16 + l15;
          float v = acc[mi][nt][r4];
          if (s < 49) {
            if (t < 49) {
              const int dh = t / 7 - s / 7 + 6;
              const int dw = t % 7 - s % 7 + 6;
              v += bias_table[(dh * 13 + dw) * 4 + h] + mw[t * 49 + s];
            }
          } else {
            v = 0.0f;  // padded cols must not contribute to PV
          }
          *(short*)(smem + ATT_OFF + h * 8192 + t * 128 + swz(t, s * 2)) = f2bf(v);
        }
      }
    }
  }
  __syncthreads();

  // ---------- phase 3: out2 = attn @ v (per head) ----------
  {
    const int h = wv >> 1, mh = wv & 1;
    f32x4 acc[2][2];
#pragma unroll
    for (int mi = 0; mi < 2; ++mi)
#pragma unroll
      for (int nt = 0; nt < 2; ++nt) { acc[mi][nt][0] = 0.f; acc[mi][nt][1] = 0.f; acc[mi][nt][2] = 0.f; acc[mi][nt][3] = 0.f; }
#pragma unroll
    for (int kk = 0; kk < 2; ++kk) {
      bf16x8 aa[2], bb[2];
#pragma unroll
      for (int mi = 0; mi < 2; ++mi) {
        const int t = (mh * 2 + mi) * 16 + l15;
        aa[mi] = *(const bf16x8*)(smem + ATT_OFF + h * 8192 + t * 128 + swz(t, kk * 64 + kg * 16));
      }
#pragma unroll
      for (int nt = 0; nt < 2; ++nt) {
        const int d = nt * 16 + l15;
        bb[nt] = *(const bf16x8*)(smem + VT_OFF + h * 4096 + d * 128 + swz(d, kk * 64 + kg * 16));
      }
#pragma unroll
      for (int mi = 0; mi < 2; ++mi)
#pragma unroll
        for (int nt = 0; nt < 2; ++nt)
          acc[mi][nt] = MFMA16(aa[mi], bb[nt], acc[mi][nt]);
    }
#pragma unroll
    for (int mi = 0; mi < 2; ++mi) {
#pragma unroll
      for (int nt = 0; nt < 2; ++nt) {
#pragma unroll
        for (int r4 = 0; r4 < 4; ++r4) {
          const int t = (mh * 2 + mi) * 16 + kg * 4 + r4;
          const int cc = h * 32 + nt * 16 + l15;
          *(short*)(smem + O2_OFF + t * 256 + swz(t, cc * 2)) = f2bf(acc[mi][nt][r4]);
        }
      }
    }
  }
  __syncthreads();

  // ---------- phase 4: out = o2 @ proj_w^T + proj_b ----------
  // wave wv owns output cols [wv*16, wv*16+16)
  {
    const int c = wv * 16 + l15;
    bf16x8 bp[4];
#pragma unroll
    for (int kk = 0; kk < 4; ++kk)
      bp[kk] = *(const bf16x8*)(wp + (size_t)c * 128 + kk * 32 + kg * 8);
    f32x4 acc[4];
#pragma unroll
    for (int m = 0; m < 4; ++m) { acc[m][0] = 0.f; acc[m][1] = 0.f; acc[m][2] = 0.f; acc[m][3] = 0.f; }
#pragma unroll
    for (int kk = 0; kk < 4; ++kk) {
#pragma unroll
      for (int m = 0; m < 4; ++m) {
        const int t = m * 16 + l15;
        bf16x8 af = *(const bf16x8*)(smem + O2_OFF + t * 256 + swz(t, kk * 64 + kg * 16));
        acc[m] = MFMA16(af, bp[kk], acc[m]);
      }
    }
    const float pb = proj_b[c];
    float* ob = out + (size_t)b * 6272 + c;
#pragma unroll
    for (int m = 0; m < 4; ++m) {
#pragma unroll
      for (int r4 = 0; r4 < 4; ++r4) {
        const int t = m * 16 + kg * 4 + r4;
        if (t < 49) ob[(size_t)t * 128] = acc[m][r4] + pb;
      }
    }
  }
}

extern "C" void kernel_launch(void* const* d_in, const int* in_sizes, int n_in,
                              void* d_out, int out_size, void* d_ws, size_t ws_size,
                              hipStream_t stream) {
  const float* x = (const float*)d_in[0];
  const float* mask = (const float*)d_in[1];
  const float* qkv_w = (const float*)d_in[2];
  const float* qkv_b = (const float*)d_in[3];
  const float* proj_w = (const float*)d_in[4];
  const float* proj_b = (const float*)d_in[5];
  const float* bias_table = (const float*)d_in[6];

  short* wq = (short*)d_ws;         // 49152 bf16
  short* wp = wq + 49152;           // 16384 bf16

  (void)hipFuncSetAttribute((const void*)wattn_fused,
                            hipFuncAttributeMaxDynamicSharedMemorySize, SMEM_BYTES);

  wattn_prep<<<192, 256, 0, stream>>>(qkv_w, proj_w, wq, wp);
  wattn_fused<<<8192, 512, SMEM_BYTES, stream>>>(x, mask, qkv_b, proj_b, bias_table,
                                                 wq, wp, (float*)d_out);
}